// Round 12
// baseline (419.264 us; speedup 1.0000x reference)
//
#include <hip/hip_runtime.h>

#define B_   2048
#define F_   64
#define H_   768
#define H4_  192   // H_/4

// Native clang vector type — __builtin_nontemporal_store requires a native
// vector, not HIP_vector_type<float,4> (compile error on gfx950 otherwise).
typedef float f4 __attribute__((ext_vector_type(4)));

// Static device-side tables — avoids any dependency on ws_size.
// Fully rewritten by precompute_kernel on every kernel_launch call, so the
// harness's input-restore / re-poison cycle cannot leave stale state.
__device__ float g_Wg[F_ * H_];     // (W - mW) * emb_g   [192 KB]
__device__ float g_Cg[F_ * H_];     // (C - mC) * emb_g   [192 KB]
__device__ float g_stats[3 * F_];   // varW, covWC, varC

// ---------------------------------------------------------------------------
// Kernel A (tiny): per-feature-f precompute.
//   C[f,h] = b[f,h] + pos[f,h] + tok[0,h]
//   mW[f]=mean_h W, mC[f]=mean_h C
//   stats: varW[f], covWC[f], varC[f]   (population, ddof=0 like jnp.var)
//   Wg[f,h] = (W-mW)*emb_g[h];  Cg[f,h] = (C-mC)*emb_g[h]
// ---------------------------------------------------------------------------
__global__ __launch_bounds__(256) void precompute_kernel(
    const float* __restrict__ W, const float* __restrict__ bb,
    const float* __restrict__ pos, const float* __restrict__ tok,
    const float* __restrict__ g)
{
    const int f = blockIdx.x;
    const int t = threadIdx.x;

    float w[3], c[3];
    float sW = 0.f, sW2 = 0.f, sC = 0.f, sC2 = 0.f, sWC = 0.f;
#pragma unroll
    for (int i = 0; i < 3; ++i) {
        const int h = t + i * 256;
        const float wv = W[f * H_ + h];
        const float cv = bb[f * H_ + h] + pos[f * H_ + h] + tok[h];
        w[i] = wv; c[i] = cv;
        sW += wv; sW2 += wv * wv; sC += cv; sC2 += cv * cv; sWC += wv * cv;
    }
    // wave-64 butterfly reduce
#pragma unroll
    for (int o = 32; o > 0; o >>= 1) {
        sW  += __shfl_xor(sW,  o, 64);
        sW2 += __shfl_xor(sW2, o, 64);
        sC  += __shfl_xor(sC,  o, 64);
        sC2 += __shfl_xor(sC2, o, 64);
        sWC += __shfl_xor(sWC, o, 64);
    }
    __shared__ float red[4][5];
    __shared__ float bc[2];
    const int wid = t >> 6, lane = t & 63;
    if (lane == 0) {
        red[wid][0] = sW; red[wid][1] = sW2; red[wid][2] = sC;
        red[wid][3] = sC2; red[wid][4] = sWC;
    }
    __syncthreads();
    if (t == 0) {
        float tW = 0.f, tW2 = 0.f, tC = 0.f, tC2 = 0.f, tWC = 0.f;
#pragma unroll
        for (int i = 0; i < 4; ++i) {
            tW += red[i][0]; tW2 += red[i][1]; tC += red[i][2];
            tC2 += red[i][3]; tWC += red[i][4];
        }
        const float inv = 1.0f / (float)H_;
        const float mW = tW * inv, mC = tC * inv;
        g_stats[f]           = tW2 * inv - mW * mW;   // varW
        g_stats[F_ + f]      = tWC * inv - mW * mC;   // covWC
        g_stats[2 * F_ + f]  = tC2 * inv - mC * mC;   // varC
        bc[0] = mW; bc[1] = mC;
    }
    __syncthreads();
    const float mW = bc[0], mC = bc[1];
#pragma unroll
    for (int i = 0; i < 3; ++i) {
        const int h = t + i * 256;
        const float gv = g[h];
        g_Wg[f * H_ + h] = (w[i] - mW) * gv;
        g_Cg[f * H_ + h] = (c[i] - mC) * gv;
    }
}

// ---------------------------------------------------------------------------
// Kernel B (hot, write-BW bound): one block per batch row b.
//   Wave 0: first LayerNorm over F=64 (shuffle reduce) ->
//           a[f] = xn*r,  r[f] = rsqrt(xn^2*varW + 2*xn*cov + varC + 1e-12)
//   All 192 threads: out[b,f,h] = a[f]*Wg[f,h] + r[f]*Cg[f,h] + emb_b[h]
//   as float4 loads + native-vector nontemporal stores (output is
//   stream-once; keep Wg/Cg resident in L2 instead).
// ---------------------------------------------------------------------------
__global__ __launch_bounds__(192) void fused_kernel(
    const float* __restrict__ x, const float* __restrict__ ln_g,
    const float* __restrict__ ln_b, const float* __restrict__ emb_b,
    float* __restrict__ out)
{
    const int b = blockIdx.x;
    const int t = threadIdx.x;
    __shared__ float sh_a[F_];
    __shared__ float sh_r[F_];

    if (t < 64) {
        const float xv = x[b * F_ + t];
        float s = xv, s2 = xv * xv;
#pragma unroll
        for (int o = 32; o > 0; o >>= 1) {
            s  += __shfl_xor(s,  o, 64);
            s2 += __shfl_xor(s2, o, 64);
        }
        const float mu  = s * (1.0f / (float)F_);
        const float var = s2 * (1.0f / (float)F_) - mu * mu;
        const float xn  = (xv - mu) * rsqrtf(var + 1e-5f) * ln_g[t] + ln_b[t];

        const float vW  = g_stats[t];
        const float cov = g_stats[F_ + t];
        const float vC  = g_stats[2 * F_ + t];
        const float vy  = fmaf(xn * xn, vW, fmaf(2.0f * xn, cov, vC));
        const float r   = rsqrtf(vy + 1e-12f);
        sh_a[t] = xn * r;
        sh_r[t] = r;
    }
    __syncthreads();

    const f4  b2  = reinterpret_cast<const f4*>(emb_b)[t];
    const f4* Wg4 = reinterpret_cast<const f4*>(g_Wg);
    const f4* Cg4 = reinterpret_cast<const f4*>(g_Cg);
    f4* out4 = reinterpret_cast<f4*>(out) + (size_t)b * (F_ * H4_);

#pragma unroll 8
    for (int f = 0; f < F_; ++f) {
        const float af = sh_a[f];
        const float rf = sh_r[f];
        const f4 wg = Wg4[f * H4_ + t];
        const f4 cg = Cg4[f * H4_ + t];
        f4 o;
        o.x = fmaf(af, wg.x, fmaf(rf, cg.x, b2.x));
        o.y = fmaf(af, wg.y, fmaf(rf, cg.y, b2.y));
        o.z = fmaf(af, wg.z, fmaf(rf, cg.z, b2.z));
        o.w = fmaf(af, wg.w, fmaf(rf, cg.w, b2.w));
        __builtin_nontemporal_store(o, &out4[f * H4_ + t]);
    }
}

extern "C" void kernel_launch(void* const* d_in, const int* in_sizes, int n_in,
                              void* d_out, int out_size, void* d_ws, size_t ws_size,
                              hipStream_t stream)
{
    const float* x    = (const float*)d_in[0];
    const float* ln_g = (const float*)d_in[1];
    const float* ln_b = (const float*)d_in[2];
    const float* W    = (const float*)d_in[3];
    const float* bb   = (const float*)d_in[4];
    const float* pos  = (const float*)d_in[5];
    const float* tok  = (const float*)d_in[6];
    const float* eg   = (const float*)d_in[7];
    const float* eb   = (const float*)d_in[8];
    float* out = (float*)d_out;

    precompute_kernel<<<F_, 256, 0, stream>>>(W, bb, pos, tok, eg);
    fused_kernel<<<B_, 192, 0, stream>>>(x, ln_g, ln_b, eb, out);
}